// Round 8
// baseline (393.708 us; speedup 1.0000x reference)
//
#include <hip/hip_runtime.h>

// GraphSAGE 2-layer: N=50000, D=128, DEG=16.
// R10: single persistent kernel (prep -> gridbar -> layer1 -> gridbar -> layer2)
//      with hand-rolled device-scope atomic barrier (cooperative launch doesn't
//      graph-capture). 1024 blocks @ __launch_bounds__(256,4) + 18.9KB LDS =
//      exactly co-resident -> no deadlock. Eliminates 2 kernel boundaries
//      (~23 us each, measured across R2/R6/R7/R9 fits). Tile code = R9 verbatim
//      (fp8 gather table, fragment-packed weights, paired epilogue stores).
typedef __attribute__((ext_vector_type(8))) short short8;
typedef __attribute__((ext_vector_type(4))) float f32x4;
typedef __attribute__((ext_vector_type(2))) float f32x2;

#define N_NODES 50000
#define D 128
#define DEG 16
#define BM 32
#define GRID 1024
#define NTILES 1563        // ceil(50000/32)
#define PREP_UNITS 3157    // 32 W-pack units + 3125 x-convert units (2048 floats)

static __device__ __forceinline__ unsigned short f2b(float f) {
    union { float f; unsigned int u; } v; v.f = f;
    return (unsigned short)((v.u + 0x7fffu + ((v.u >> 16) & 1u)) >> 16);
}

// device-scope grid barrier; cnt zeroed per replay by memset node.
static __device__ __forceinline__ void gridbar(unsigned* cnt) {
    __syncthreads();
    if (threadIdx.x == 0) {
        __threadfence();   // release: writeback this XCD's L2
        __hip_atomic_fetch_add(cnt, 1u, __ATOMIC_RELEASE, __HIP_MEMORY_SCOPE_AGENT);
        while (__hip_atomic_load(cnt, __ATOMIC_RELAXED, __HIP_MEMORY_SCOPE_AGENT) < GRID)
            __builtin_amdgcn_s_sleep(8);
        __threadfence();   // acquire: invalidate stale L1/L2 lines
    }
    __syncthreads();
}

// W1,W2 ((2D,D) row-major) -> fragment order:
//   o = w*8192 + kk*1024 + ct*512 + lane*8 + e  (shorts)
//   k = kk*32 + (lane>>4)*8 + e,  n = w*32 + 2*(lane&15) + ct  (col-interleaved)
static __device__ __forceinline__ void prep_unit(
    int u, int tid, const float* __restrict__ x,
    const float* __restrict__ W1, const float* __restrict__ W2,
    unsigned short* __restrict__ xb, unsigned char* __restrict__ xq,
    unsigned short* __restrict__ Wf1, unsigned short* __restrict__ Wf2)
{
    if (u < 32) {
        int o  = (u * 256 + tid) * 4;
        int e0 = o & 7;
        int l  = (o >> 3) & 63;
        int ct = (o >> 9) & 1;
        int kk = (o >> 10) & 7;
        int w  = o >> 13;
        int n  = w * 32 + ((l & 15) << 1) + ct;
        int kb = kk * 32 + (l >> 4) * 8 + e0;
        ushort4 a, c;
        a.x = f2b(W1[(kb + 0) * D + n]);
        a.y = f2b(W1[(kb + 1) * D + n]);
        a.z = f2b(W1[(kb + 2) * D + n]);
        a.w = f2b(W1[(kb + 3) * D + n]);
        *(ushort4*)(Wf1 + o) = a;
        c.x = f2b(W2[(kb + 0) * D + n]);
        c.y = f2b(W2[(kb + 1) * D + n]);
        c.z = f2b(W2[(kb + 2) * D + n]);
        c.w = f2b(W2[(kb + 3) * D + n]);
        *(ushort4*)(Wf2 + o) = c;
    } else {
        int i = (u - 32) * 2048 + tid * 8;   // 3125 units x 2048 = 6.4M exact
        float4 v0 = *(const float4*)(x + i);
        float4 v1 = *(const float4*)(x + i + 4);
        union { unsigned short u[8]; short8 s8; } m;
        m.u[0] = f2b(v0.x); m.u[1] = f2b(v0.y); m.u[2] = f2b(v0.z); m.u[3] = f2b(v0.w);
        m.u[4] = f2b(v1.x); m.u[5] = f2b(v1.y); m.u[6] = f2b(v1.z); m.u[7] = f2b(v1.w);
        *(short8*)(xb + i) = m.s8;
        int q0 = __builtin_amdgcn_cvt_pk_fp8_f32(v0.x, v0.y, 0, false);
        q0 = __builtin_amdgcn_cvt_pk_fp8_f32(v0.z, v0.w, q0, true);
        int q1 = __builtin_amdgcn_cvt_pk_fp8_f32(v1.x, v1.y, 0, false);
        q1 = __builtin_amdgcn_cvt_pk_fp8_f32(v1.z, v1.w, q1, true);
        uint2 qq; qq.x = (unsigned)q0; qq.y = (unsigned)q1;
        *(uint2*)(xq + i) = qq;
    }
}

// one BM=32 output tile: out = relu( [feat | mean_nbr(featq)] @ W + b )
template <int OUT_BF16>
static __device__ __forceinline__ void layer_tile(
    int t, const unsigned short* __restrict__ feat,
    const unsigned char* __restrict__ featq,
    const int* __restrict__ nbr, const unsigned short* __restrict__ wf,
    const float* __restrict__ bias, void* __restrict__ out,
    unsigned char* __restrict__ outq, unsigned short* Hl, int* Nl)
{
    const int tid  = threadIdx.x;
    const int row0 = t * BM;

    __syncthreads();                         // LDS reuse guard across tiles
    if (tid < 128) {
        int g = row0 * DEG + tid * 4;
        int gmax = N_NODES * DEG - 4;
        if (g > gmax) g = gmax;              // tail clamp; extra rows unused
        *(int4*)(Nl + tid * 4) = *(const int4*)(nbr + g);
    }
    __syncthreads();

    const char* fb = (const char*)feat;      // bf16 rows: 256B
    const char* qb = (const char*)featq;     // fp8 rows: 128B

    #pragma unroll
    for (int p = 0; p < 2; ++p) {
        int a = tid + p * 256;
        int r = a >> 4;                      // 0..31
        int s = a & 15;                      // 8-dim slice
        int grow = row0 + r;
        if (grow >= N_NODES) grow = N_NODES - 1;
        short8 self = *(const short8*)(fb + (unsigned)grow * 256u + (unsigned)s * 16u);

        int4 i0 = *(const int4*)(Nl + r * 16);
        int4 i1 = *(const int4*)(Nl + r * 16 + 4);
        int4 i2 = *(const int4*)(Nl + r * 16 + 8);
        int4 i3 = *(const int4*)(Nl + r * 16 + 12);
        int ids[16] = { i0.x, i0.y, i0.z, i0.w, i1.x, i1.y, i1.z, i1.w,
                        i2.x, i2.y, i2.z, i2.w, i3.x, i3.y, i3.z, i3.w };

        uint2 v[16];
        #pragma unroll
        for (int j = 0; j < 16; ++j)
            v[j] = *(const uint2*)(qb + (((unsigned)ids[j]) << 7) + (unsigned)s * 8u);

        f32x2 am[4];
        #pragma unroll
        for (int i = 0; i < 4; ++i) am[i] = (f32x2){0.f, 0.f};
        #pragma unroll
        for (int j = 0; j < 16; ++j) {
            am[0] += __builtin_amdgcn_cvt_pk_f32_fp8(v[j].x, false);
            am[1] += __builtin_amdgcn_cvt_pk_f32_fp8(v[j].x, true);
            am[2] += __builtin_amdgcn_cvt_pk_f32_fp8(v[j].y, false);
            am[3] += __builtin_amdgcn_cvt_pk_f32_fp8(v[j].y, true);
        }

        unsigned short* hr = Hl + r * 264 + s * 8;
        *(short8*)(hr) = self;
        union { unsigned short u[8]; short8 s8; } m;
        #pragma unroll
        for (int i = 0; i < 4; ++i) {
            m.u[2 * i]     = f2b(am[i].x * 0.0625f);
            m.u[2 * i + 1] = f2b(am[i].y * 0.0625f);
        }
        *(short8*)(hr + D) = m.s8;
    }

    const int lane = tid & 63;
    const int w    = tid >> 6;
    const int quad = lane >> 4;
    const int l16  = lane & 15;
    const unsigned short* wfw = wf + w * 8192;
    short8 bfrag[8][2];
    #pragma unroll
    for (int kk = 0; kk < 8; ++kk)
        #pragma unroll
        for (int ct = 0; ct < 2; ++ct)
            bfrag[kk][ct] = *(const short8*)(wfw + kk * 1024 + ct * 512 + lane * 8);

    __syncthreads();

    f32x4 acc[2][2];
    #pragma unroll
    for (int rt = 0; rt < 2; ++rt)
        #pragma unroll
        for (int ct = 0; ct < 2; ++ct)
            acc[rt][ct] = (f32x4){0.f, 0.f, 0.f, 0.f};

    #pragma unroll
    for (int kk = 0; kk < 8; ++kk) {
        short8 af[2];
        #pragma unroll
        for (int rt = 0; rt < 2; ++rt)
            af[rt] = *(const short8*)(&Hl[(rt * 16 + l16) * 264 + kk * 32 + quad * 8]);
        #pragma unroll
        for (int rt = 0; rt < 2; ++rt)
            #pragma unroll
            for (int ct = 0; ct < 2; ++ct)
                acc[rt][ct] = __builtin_amdgcn_mfma_f32_16x16x32_bf16(
                    af[rt], bfrag[kk][ct], acc[rt][ct], 0, 0, 0);
    }

    const int col0 = w * 32 + (l16 << 1);
    float2 bv = *(const float2*)(bias + col0);
    #pragma unroll
    for (int rt = 0; rt < 2; ++rt) {
        int gb = row0 + rt * 16 + quad * 4;
        #pragma unroll
        for (int r = 0; r < 4; ++r) {
            int grow = gb + r;
            if (grow >= N_NODES) continue;
            float v0 = acc[rt][0][r] + bv.x;
            float v1 = acc[rt][1][r] + bv.y;
            v0 = v0 > 0.f ? v0 : 0.f;
            v1 = v1 > 0.f ? v1 : 0.f;
            if (OUT_BF16) {
                unsigned u = (unsigned)f2b(v0) | ((unsigned)f2b(v1) << 16);
                *(unsigned*)((unsigned short*)out + grow * D + col0) = u;
                int q = __builtin_amdgcn_cvt_pk_fp8_f32(v0, v1, 0, false);
                *(unsigned short*)(outq + grow * D + col0) = (unsigned short)q;
            } else {
                f32x2 o2; o2.x = v0; o2.y = v1;
                *(f32x2*)((float*)out + grow * D + col0) = o2;
            }
        }
    }
}

__global__ __launch_bounds__(256, 4)
void fused(const float* __restrict__ x, const int* __restrict__ nbr,
           const float* __restrict__ W1, const float* __restrict__ b1,
           const float* __restrict__ W2, const float* __restrict__ b2,
           unsigned short* __restrict__ xb, unsigned char* __restrict__ xq,
           unsigned short* __restrict__ h1, unsigned char* __restrict__ h1q,
           unsigned short* __restrict__ Wf1, unsigned short* __restrict__ Wf2,
           float* __restrict__ out, unsigned* __restrict__ cnt)
{
    __shared__ __align__(16) unsigned short Hl[BM * 264];  // 16896 B
    __shared__ __align__(16) int Nl[BM * DEG];             //  2048 B
    const int bid = blockIdx.x;
    const int tid = threadIdx.x;

    // phase A: prep (W pack + x -> bf16/fp8)
    for (int u = bid; u < PREP_UNITS; u += GRID)
        prep_unit(u, tid, x, W1, W2, xb, xq, Wf1, Wf2);

    gridbar(cnt + 0);

    // phase B: layer 1 -> h1 (bf16) + h1q (fp8)
    for (int t = bid; t < NTILES; t += GRID)
        layer_tile<1>(t, xb, xq, nbr, Wf1, b1, (void*)h1, h1q, Hl, Nl);

    gridbar(cnt + 32);   // separate cache line

    // phase C: layer 2 -> out (f32)
    for (int t = bid; t < NTILES; t += GRID)
        layer_tile<0>(t, h1, h1q, nbr, Wf2, b2, (void*)out, nullptr, Hl, Nl);
}

extern "C" void kernel_launch(void* const* d_in, const int* in_sizes, int n_in,
                              void* d_out, int out_size, void* d_ws, size_t ws_size,
                              hipStream_t stream) {
    const float* x  = (const float*)d_in[0];
    const int*   nb = (const int*)d_in[1];
    const float* W1 = (const float*)d_in[2];
    const float* b1 = (const float*)d_in[3];
    const float* W2 = (const float*)d_in[4];
    const float* b2 = (const float*)d_in[5];

    char* ws = (char*)d_ws;
    unsigned short* Wf1 = (unsigned short*)(ws);                       // 64 KB
    unsigned short* Wf2 = (unsigned short*)(ws + 65536);               // 64 KB
    unsigned short* xb  = (unsigned short*)(ws + 131072);              // 12.8 MB
    unsigned short* h1  = (unsigned short*)(ws + 131072 + 12800000);   // 12.8 MB
    unsigned char*  xq  = (unsigned char*)(ws + 131072 + 25600000);    // 6.4 MB
    unsigned char*  h1q = (unsigned char*)(ws + 131072 + 32000000);    // 6.4 MB
    unsigned*       cnt = (unsigned*)(ws + 40000000);                  // barrier counters

    hipMemsetAsync((void*)cnt, 0, 256, stream);   // zero counters each replay

    fused<<<GRID, 256, 0, stream>>>(x, nb, W1, b1, W2, b2,
                                    xb, xq, h1, h1q, Wf1, Wf2,
                                    (float*)d_out, cnt);
}

// Round 9
// 125.605 us; speedup vs baseline: 3.1345x; 3.1345x over previous
//
#include <hip/hip_runtime.h>

// GraphSAGE 2-layer: N=50000, D=128, DEG=16.
// R11: R9 structure (3 launches; fp8 gather table; fragment-packed weights;
//      paired epilogue stores) + merged gather slots: each thread issues all
//      32 neighbor loads (rows r and r+16, same slice) before converting ->
//      2x memory-level parallelism in the latency-bound gather (R10 counters
//      showed the layer is idle-latency-bound, VALU/MFMA/HBM all <6%).
typedef __attribute__((ext_vector_type(8))) short short8;
typedef __attribute__((ext_vector_type(4))) float f32x4;
typedef __attribute__((ext_vector_type(2))) float f32x2;

#define N_NODES 50000
#define D 128
#define DEG 16
#define BM 32

static __device__ __forceinline__ unsigned short f2b(float f) {
    union { float f; unsigned int u; } v; v.f = f;
    return (unsigned short)((v.u + 0x7fffu + ((v.u >> 16) & 1u)) >> 16);
}

// ---- prep ----
// blocks 0..31: pack W1,W2 ((2D,D) row-major) into fragment order:
//   o = w*8192 + kk*1024 + ct*512 + lane*8 + e  (shorts)
//   k = kk*32 + (lane>>4)*8 + e,  n = w*32 + 2*(lane&15) + ct  (col-interleaved)
// blocks 32..: x -> bf16 (xb) and fp8-e4m3 (xq).
__global__ void prep(const float* __restrict__ x, unsigned short* __restrict__ xb,
                     unsigned char* __restrict__ xq,
                     const float* __restrict__ W1, const float* __restrict__ W2,
                     unsigned short* __restrict__ Wf1, unsigned short* __restrict__ Wf2) {
    int b = blockIdx.x;
    if (b < 32) {
        int o  = (b * 256 + threadIdx.x) * 4;
        int e0 = o & 7;
        int l  = (o >> 3) & 63;
        int ct = (o >> 9) & 1;
        int kk = (o >> 10) & 7;
        int w  = o >> 13;
        int n  = w * 32 + ((l & 15) << 1) + ct;
        int kb = kk * 32 + (l >> 4) * 8 + e0;
        ushort4 a, c;
        a.x = f2b(W1[(kb + 0) * D + n]);
        a.y = f2b(W1[(kb + 1) * D + n]);
        a.z = f2b(W1[(kb + 2) * D + n]);
        a.w = f2b(W1[(kb + 3) * D + n]);
        *(ushort4*)(Wf1 + o) = a;
        c.x = f2b(W2[(kb + 0) * D + n]);
        c.y = f2b(W2[(kb + 1) * D + n]);
        c.z = f2b(W2[(kb + 2) * D + n]);
        c.w = f2b(W2[(kb + 3) * D + n]);
        *(ushort4*)(Wf2 + o) = c;
    } else {
        int i = ((b - 32) * 256 + threadIdx.x) * 4;
        if (i < N_NODES * D) {
            float4 v = *(const float4*)(x + i);
            ushort4 o4;
            o4.x = f2b(v.x); o4.y = f2b(v.y); o4.z = f2b(v.z); o4.w = f2b(v.w);
            *(ushort4*)(xb + i) = o4;
            int q = __builtin_amdgcn_cvt_pk_fp8_f32(v.x, v.y, 0, false);
            q = __builtin_amdgcn_cvt_pk_fp8_f32(v.z, v.w, q, true);
            *(unsigned*)(xq + i) = (unsigned)q;
        }
    }
}

// ---- fused layer: out = relu( [feat | mean_nbr(feat_q)] @ W + b ) ----
// OUT_BF16=1: write bf16 (h1) + fp8 (h1q). OUT_BF16=0: write f32 final.
template <int OUT_BF16>
__global__ __launch_bounds__(256, 4)
void sage_layer(const unsigned short* __restrict__ feat,   // N x D bf16
                const unsigned char* __restrict__ featq,   // N x D fp8
                const int* __restrict__ nbr,               // N x DEG
                const unsigned short* __restrict__ wf,     // fragment-packed bf16
                const float* __restrict__ bias,            // D f32
                void* __restrict__ out,
                unsigned char* __restrict__ outq)          // N x D fp8 (OUT_BF16)
{
    __shared__ __align__(16) unsigned short Hl[BM * 264];  // A tile, row stride 264
    __shared__ int Nl[BM * DEG];                           // 512 neighbor ids
    const int tid  = threadIdx.x;
    const int row0 = blockIdx.x * BM;

    if (tid < 128) {
        int g = row0 * DEG + tid * 4;
        int gmax = N_NODES * DEG - 4;
        if (g > gmax) g = gmax;              // tail clamp; extra rows unused
        *(int4*)(Nl + tid * 4) = *(const int4*)(nbr + g);
    }
    __syncthreads();

    const char* fb = (const char*)feat;      // bf16 rows: 256B
    const char* qb = (const char*)featq;     // fp8 rows: 128B

    // ---- gather: merged slots (rows r0 and r0+16, same slice s).
    // All 32 neighbor loads + 2 self loads issued before any conversion.
    {
        const int r0 = tid >> 4;             // 0..15
        const int r1 = r0 + 16;              // 16..31
        const int s  = tid & 15;
        const unsigned sB16 = (unsigned)s * 16u;
        const unsigned sB8  = (unsigned)s * 8u;

        int g0 = row0 + r0; if (g0 >= N_NODES) g0 = N_NODES - 1;
        int g1 = row0 + r1; if (g1 >= N_NODES) g1 = N_NODES - 1;
        short8 self0 = *(const short8*)(fb + (unsigned)g0 * 256u + sB16);
        short8 self1 = *(const short8*)(fb + (unsigned)g1 * 256u + sB16);

        int4 a0 = *(const int4*)(Nl + r0 * 16);
        int4 a1 = *(const int4*)(Nl + r0 * 16 + 4);
        int4 a2 = *(const int4*)(Nl + r0 * 16 + 8);
        int4 a3 = *(const int4*)(Nl + r0 * 16 + 12);
        int4 c0 = *(const int4*)(Nl + r1 * 16);
        int4 c1 = *(const int4*)(Nl + r1 * 16 + 4);
        int4 c2 = *(const int4*)(Nl + r1 * 16 + 8);
        int4 c3 = *(const int4*)(Nl + r1 * 16 + 12);
        int ids0[16] = { a0.x, a0.y, a0.z, a0.w, a1.x, a1.y, a1.z, a1.w,
                         a2.x, a2.y, a2.z, a2.w, a3.x, a3.y, a3.z, a3.w };
        int ids1[16] = { c0.x, c0.y, c0.z, c0.w, c1.x, c1.y, c1.z, c1.w,
                         c2.x, c2.y, c2.z, c2.w, c3.x, c3.y, c3.z, c3.w };

        uint2 v0[16], v1[16];
        #pragma unroll
        for (int j = 0; j < 16; ++j)
            v0[j] = *(const uint2*)(qb + (((unsigned)ids0[j]) << 7) + sB8);
        #pragma unroll
        for (int j = 0; j < 16; ++j)
            v1[j] = *(const uint2*)(qb + (((unsigned)ids1[j]) << 7) + sB8);

        f32x2 am0[4], am1[4];
        #pragma unroll
        for (int i = 0; i < 4; ++i) { am0[i] = (f32x2){0.f, 0.f}; am1[i] = (f32x2){0.f, 0.f}; }
        #pragma unroll
        for (int j = 0; j < 16; ++j) {
            am0[0] += __builtin_amdgcn_cvt_pk_f32_fp8(v0[j].x, false);
            am0[1] += __builtin_amdgcn_cvt_pk_f32_fp8(v0[j].x, true);
            am0[2] += __builtin_amdgcn_cvt_pk_f32_fp8(v0[j].y, false);
            am0[3] += __builtin_amdgcn_cvt_pk_f32_fp8(v0[j].y, true);
        }
        #pragma unroll
        for (int j = 0; j < 16; ++j) {
            am1[0] += __builtin_amdgcn_cvt_pk_f32_fp8(v1[j].x, false);
            am1[1] += __builtin_amdgcn_cvt_pk_f32_fp8(v1[j].x, true);
            am1[2] += __builtin_amdgcn_cvt_pk_f32_fp8(v1[j].y, false);
            am1[3] += __builtin_amdgcn_cvt_pk_f32_fp8(v1[j].y, true);
        }

        unsigned short* hr0 = Hl + r0 * 264 + s * 8;
        unsigned short* hr1 = Hl + r1 * 264 + s * 8;
        *(short8*)(hr0) = self0;
        *(short8*)(hr1) = self1;
        union { unsigned short u[8]; short8 s8; } m0, m1;
        #pragma unroll
        for (int i = 0; i < 4; ++i) {
            m0.u[2 * i]     = f2b(am0[i].x * 0.0625f);
            m0.u[2 * i + 1] = f2b(am0[i].y * 0.0625f);
            m1.u[2 * i]     = f2b(am1[i].x * 0.0625f);
            m1.u[2 * i + 1] = f2b(am1[i].y * 0.0625f);
        }
        *(short8*)(hr0 + D) = m0.s8;
        *(short8*)(hr1 + D) = m1.s8;
    }

    // ---- B fragments (fragment-packed: 64 lanes x 16B contiguous per load)
    const int lane = tid & 63;
    const int w    = tid >> 6;
    const int quad = lane >> 4;
    const int l16  = lane & 15;
    const unsigned short* wfw = wf + w * 8192;
    short8 bfrag[8][2];
    #pragma unroll
    for (int kk = 0; kk < 8; ++kk)
        #pragma unroll
        for (int ct = 0; ct < 2; ++ct)
            bfrag[kk][ct] = *(const short8*)(wfw + kk * 1024 + ct * 512 + lane * 8);

    __syncthreads();

    // ---- MFMA: 32 rows (2 rt) x 32 cols (2 ct, col-interleaved) per wave
    f32x4 acc[2][2];
    #pragma unroll
    for (int rt = 0; rt < 2; ++rt)
        #pragma unroll
        for (int ct = 0; ct < 2; ++ct)
            acc[rt][ct] = (f32x4){0.f, 0.f, 0.f, 0.f};

    #pragma unroll
    for (int kk = 0; kk < 8; ++kk) {
        short8 af[2];
        #pragma unroll
        for (int rt = 0; rt < 2; ++rt)
            af[rt] = *(const short8*)(&Hl[(rt * 16 + l16) * 264 + kk * 32 + quad * 8]);
        #pragma unroll
        for (int rt = 0; rt < 2; ++rt)
            #pragma unroll
            for (int ct = 0; ct < 2; ++ct)
                acc[rt][ct] = __builtin_amdgcn_mfma_f32_16x16x32_bf16(
                    af[rt], bfrag[kk][ct], acc[rt][ct], 0, 0, 0);
    }

    // ---- epilogue: adjacent col pair (col0, col0+1) per thread
    const int col0 = w * 32 + (l16 << 1);
    float2 bv = *(const float2*)(bias + col0);
    #pragma unroll
    for (int rt = 0; rt < 2; ++rt) {
        int gb = row0 + rt * 16 + quad * 4;
        #pragma unroll
        for (int r = 0; r < 4; ++r) {
            int grow = gb + r;
            if (grow >= N_NODES) continue;
            float v0 = acc[rt][0][r] + bv.x;
            float v1 = acc[rt][1][r] + bv.y;
            v0 = v0 > 0.f ? v0 : 0.f;
            v1 = v1 > 0.f ? v1 : 0.f;
            if (OUT_BF16) {
                unsigned u = (unsigned)f2b(v0) | ((unsigned)f2b(v1) << 16);
                *(unsigned*)((unsigned short*)out + grow * D + col0) = u;
                int q = __builtin_amdgcn_cvt_pk_fp8_f32(v0, v1, 0, false);
                *(unsigned short*)(outq + grow * D + col0) = (unsigned short)q;
            } else {
                f32x2 o2; o2.x = v0; o2.y = v1;
                *(f32x2*)((float*)out + grow * D + col0) = o2;
            }
        }
    }
}

extern "C" void kernel_launch(void* const* d_in, const int* in_sizes, int n_in,
                              void* d_out, int out_size, void* d_ws, size_t ws_size,
                              hipStream_t stream) {
    const float* x  = (const float*)d_in[0];
    const int*   nb = (const int*)d_in[1];
    const float* W1 = (const float*)d_in[2];
    const float* b1 = (const float*)d_in[3];
    const float* W2 = (const float*)d_in[4];
    const float* b2 = (const float*)d_in[5];

    char* ws = (char*)d_ws;
    unsigned short* Wf1 = (unsigned short*)(ws);                       // 64 KB
    unsigned short* Wf2 = (unsigned short*)(ws + 65536);               // 64 KB
    unsigned short* xb  = (unsigned short*)(ws + 131072);              // 12.8 MB
    unsigned short* h1  = (unsigned short*)(ws + 131072 + 12800000);   // 12.8 MB
    unsigned char*  xq  = (unsigned char*)(ws + 131072 + 25600000);    // 6.4 MB
    unsigned char*  h1q = (unsigned char*)(ws + 131072 + 32000000);    // 6.4 MB

    prep<<<32 + 6250, 256, 0, stream>>>(x, xb, xq, W1, W2, Wf1, Wf2);

    const int mgrid = (N_NODES + BM - 1) / BM;  // 1563
    sage_layer<1><<<mgrid, 256, 0, stream>>>(xb, xq, nb, Wf1, b1, h1, h1q);
    sage_layer<0><<<mgrid, 256, 0, stream>>>(h1, h1q, nb, Wf2, b2, d_out, nullptr);
}